// Round 6
// baseline (360.014 us; speedup 1.0000x reference)
//
#include <hip/hip_runtime.h>
#include <hip/hip_fp16.h>
#include <math.h>

#define BB 1024
#define LSx 128
#define LLx 2048
#define TOPKx 48
#define VOCABx 160000

// ---------------------------------------------------------------------------
// Kernel 1 (k_pre): grid 625+4.
//   bid < 625 : Ph[v][seg][m] = sum_e emb[v][e]*H[seg*16+e][m]  (fp16)
//   bid >= 625: per-b item codes icodesG[b][m] = sign(sum_e Xitem[e]*H[e][m])
// ---------------------------------------------------------------------------
__global__ __launch_bounds__(256) void k_pre(
    const float* __restrict__ emb, const float* __restrict__ Hm,
    const int* __restrict__ ig, const int* __restrict__ ish, const int* __restrict__ ici,
    __half* __restrict__ Ph, int* __restrict__ icodesG)
{
  const int bid = blockIdx.x, tid = threadIdx.x;
  if (bid < 625) {
    const int v = bid * 256 + tid;
    if (v >= VOCABx) return;
    const float4* er = (const float4*)(emb + (size_t)v * 16);
    const float4 x0 = er[0], x1 = er[1], x2 = er[2], x3 = er[3];
    const float x[16] = {x0.x, x0.y, x0.z, x0.w, x1.x, x1.y, x1.z, x1.w,
                         x2.x, x2.y, x2.z, x2.w, x3.x, x3.y, x3.z, x3.w};
    unsigned int packed[24];
    #pragma unroll
    for (int seg = 0; seg < 3; ++seg) {
      #pragma unroll
      for (int mp = 0; mp < 8; ++mp) {
        float a0 = 0.f, a1 = 0.f;
        #pragma unroll
        for (int e = 0; e < 16; ++e) {
          a0 += x[e] * Hm[(seg * 16 + e) * 16 + 2 * mp];
          a1 += x[e] * Hm[(seg * 16 + e) * 16 + 2 * mp + 1];
        }
        const __half2 hp = __floats2half2_rn(a0, a1);
        packed[seg * 8 + mp] = *(const unsigned int*)&hp;
      }
    }
    uint4* dst = (uint4*)(Ph + (size_t)v * 48);
    #pragma unroll
    for (int q = 0; q < 6; ++q) {
      uint4 o;
      o.x = packed[q * 4 + 0]; o.y = packed[q * 4 + 1];
      o.z = packed[q * 4 + 2]; o.w = packed[q * 4 + 3];
      dst[q] = o;
    }
  } else {
    const int b = (bid - 625) * 256 + tid;
    if (b >= BB) return;
    const int id0 = ig[b], id1 = ish[b], id2 = ici[b];
    float xi[48];
    #pragma unroll
    for (int q = 0; q < 4; ++q) {
      const float4 a = ((const float4*)(emb + (size_t)id0 * 16))[q];
      xi[q * 4 + 0] = a.x; xi[q * 4 + 1] = a.y; xi[q * 4 + 2] = a.z; xi[q * 4 + 3] = a.w;
      const float4 bq4 = ((const float4*)(emb + (size_t)id1 * 16))[q];
      xi[16 + q * 4 + 0] = bq4.x; xi[16 + q * 4 + 1] = bq4.y; xi[16 + q * 4 + 2] = bq4.z; xi[16 + q * 4 + 3] = bq4.w;
      const float4 c4 = ((const float4*)(emb + (size_t)id2 * 16))[q];
      xi[32 + q * 4 + 0] = c4.x; xi[32 + q * 4 + 1] = c4.y; xi[32 + q * 4 + 2] = c4.z; xi[32 + q * 4 + 3] = c4.w;
    }
    #pragma unroll
    for (int m = 0; m < 16; ++m) {
      float dd = 0.f;
      for (int e = 0; e < 48; ++e) dd += xi[e] * Hm[e * 16 + m];  // e ascending = ref order
      icodesG[b * 16 + m] = (dd > 0.f) ? 1 : (dd < 0.f ? -1 : 0);
    }
  }
}

// ---------------------------------------------------------------------------
// Kernel 2 (k_codes): grid 4096 (4 blocks per b, 512 positions each), 256 thr.
// 16-lane group per position, ballot score, coalesced byte output.
// ---------------------------------------------------------------------------
__global__ __launch_bounds__(256) void k_codes(
    const int* __restrict__ lg, const int* __restrict__ lsh, const int* __restrict__ lc,
    const int* __restrict__ icodesG, const __half* __restrict__ Ph,
    signed char* __restrict__ scoresG)
{
  __shared__ int idsS[3 * 512];                // 6144 B
  __shared__ signed char sc_stage[512];        // 512 B
  const int bid = blockIdx.x, tid = threadIdx.x;
  const int b = bid >> 2, c0 = (bid & 3) * 512;

  // stage ids: 384 int4 loads
  for (int t = tid; t < 384; t += 256) {
    int4 v4;
    if (t < 128)      v4 = ((const int4*)(lg  + (size_t)b * LLx + c0))[t];
    else if (t < 256) v4 = ((const int4*)(lsh + (size_t)b * LLx + c0))[t - 128];
    else              v4 = ((const int4*)(lc  + (size_t)b * LLx + c0))[t - 256];
    ((int4*)idsS)[t] = v4;
  }
  const int l16 = tid & 15;
  const int grpw = (tid >> 4) & 3;   // group within wave
  const int grp16 = tid >> 4;        // group within block (0..15)
  const int myic = icodesG[b * 16 + l16];
  __syncthreads();

  #pragma unroll
  for (int r8 = 0; r8 < 32; r8 += 8) {
    int g_[8], s_[8], c_[8];
    #pragma unroll
    for (int u = 0; u < 8; ++u) {
      const int p = (r8 + u) * 16 + grp16;
      g_[u] = idsS[p]; s_[u] = idsS[512 + p]; c_[u] = idsS[1024 + p];
    }
    float d0[8], d1[8], d2[8];
    #pragma unroll
    for (int u = 0; u < 8; ++u) {
      d0[u] = __half2float(Ph[(size_t)g_[u] * 48 + l16]);
      d1[u] = __half2float(Ph[(size_t)s_[u] * 48 + 16 + l16]);
      d2[u] = __half2float(Ph[(size_t)c_[u] * 48 + 32 + l16]);
    }
    #pragma unroll
    for (int u = 0; u < 8; ++u) {
      const int p = (r8 + u) * 16 + grp16;
      const float d = (d0[u] + d1[u]) + d2[u];
      const int cs = (d > 0.f) ? 1 : (d < 0.f ? -1 : 0);
      const unsigned long long bal = __ballot(cs == myic);
      int sc = (int)__popcll((bal >> (16 * grpw)) & 0xFFFFull);
      if (g_[u] == 0) sc = -1;   // masked (reference: -inf)
      if (l16 == 0) sc_stage[p] = (signed char)sc;
    }
  }
  __syncthreads();
  if (tid < 128)
    ((int*)(scoresG + (size_t)b * LLx + c0))[tid] = ((const int*)sc_stage)[tid];
}

// ---------------------------------------------------------------------------
// Kernel 3 (k_att): grid 2048, 128 thr.
//   bid < 1024 : short MHA  -> sint
//   bid >= 1024: top-k from scoresG + long MHA -> lint
// ---------------------------------------------------------------------------
__global__ __launch_bounds__(128) void k_att(
    const int* __restrict__ sg, const int* __restrict__ ss, const int* __restrict__ scd,
    const int* __restrict__ lg, const int* __restrict__ ls, const int* __restrict__ lcd,
    const int* __restrict__ ig, const int* __restrict__ ish, const int* __restrict__ ici,
    const float* __restrict__ emb, const signed char* __restrict__ scoresG,
    const float* __restrict__ sWq, const float* __restrict__ sbq,
    const float* __restrict__ sWk, const float* __restrict__ sbk,
    const float* __restrict__ sWv, const float* __restrict__ sbv,
    const float* __restrict__ sWo, const float* __restrict__ sbo,
    const float* __restrict__ lWq, const float* __restrict__ lbq,
    const float* __restrict__ lWk, const float* __restrict__ lbk,
    const float* __restrict__ lWv, const float* __restrict__ lbv,
    const float* __restrict__ lWo, const float* __restrict__ lbo,
    float* __restrict__ sint, float* __restrict__ lint)
{
  __shared__ __align__(16) char pool[17280];
  const int bid = blockIdx.x, tid = threadIdx.x;
  const int lane = tid & 63, wv = tid >> 6;

  if (bid < BB) {
    // ========================= short MHA (K=128) =========================
    const int b = bid;
    __half* vhs_h = (__half*)pool;                          // 12288
    float* scs = (float*)(pool + 12288);                    // 8*132*4 = 4224
    float* Xitem = (float*)(pool + 16512);                  // 192
    float* qh = (float*)(pool + 16704);                     // 192
    float* osm = (float*)(pool + 16896);                    // 192
    unsigned char* validf = (unsigned char*)(pool + 17088); // 128

    if (tid < 48) {
      const int seg = tid >> 4, e = tid & 15;
      const int id = (seg == 0) ? ig[b] : (seg == 1) ? ish[b] : ici[b];
      Xitem[tid] = emb[(size_t)id * 16 + e];
    }
    __syncthreads();
    if (tid < 48) {
      float a = sbq[tid];
      for (int e = 0; e < 48; ++e) a += Xitem[e] * sWq[e * 48 + tid];
      qh[tid] = a;
    }
    const size_t off = (size_t)b * LSx + tid;
    const int gid = sg[off], sid = ss[off], cid = scd[off];
    const int nval = __syncthreads_count(gid != 0);   // slen
    validf[tid] = (unsigned char)(tid < nval);        // mask = pos < slen

    {
      float kh[48], vh[48];
      #pragma unroll
      for (int j = 0; j < 48; ++j) { kh[j] = sbk[j]; vh[j] = sbv[j]; }
      const int ids3[3] = {gid, sid, cid};
      #pragma unroll
      for (int seg = 0; seg < 3; ++seg) {
        const float* row = emb + (size_t)ids3[seg] * 16;
        #pragma unroll
        for (int i4 = 0; i4 < 4; ++i4) {
          const float4 xv = ((const float4*)row)[i4];
          const float xs[4] = {xv.x, xv.y, xv.z, xv.w};
          #pragma unroll
          for (int c = 0; c < 4; ++c) {
            const float* wkr = sWk + (seg * 16 + i4 * 4 + c) * 48;
            const float* wvr = sWv + (seg * 16 + i4 * 4 + c) * 48;
            const float xe = xs[c];
            #pragma unroll
            for (int j = 0; j < 48; ++j) {
              kh[j] += xe * wkr[j];
              vh[j] += xe * wvr[j];
            }
          }
        }
      }
      #pragma unroll
      for (int h = 0; h < 8; ++h) {
        float s = 0.f;
        #pragma unroll
        for (int d = 0; d < 6; ++d) s += qh[h * 6 + d] * kh[h * 6 + d];
        scs[h * 132 + tid] = s * 0.40824829046386301637f;   // 1/sqrt(6)
      }
      #pragma unroll
      for (int j = 0; j < 48; ++j) vhs_h[tid * 48 + j] = __float2half(vh[j]);
    }
    __syncthreads();

    {  // softmax: 8 groups of 16 lanes
      const int h = tid >> 4, l16 = tid & 15;
      float amax = -INFINITY;
      for (int k = l16; k < LSx; k += 16) if (validf[k]) amax = fmaxf(amax, scs[h * 132 + k]);
      #pragma unroll
      for (int m = 1; m < 16; m <<= 1) amax = fmaxf(amax, __shfl_xor(amax, m, 16));
      if (nval == 0) {
        for (int k = l16; k < LSx; k += 16) scs[h * 132 + k] = 1.0f / (float)LSx;
      } else {
        float ssum = 0.f;
        for (int k = l16; k < LSx; k += 16) {
          const float ev = validf[k] ? expf(scs[h * 132 + k] - amax) : 0.f;
          scs[h * 132 + k] = ev;
          ssum += ev;
        }
        #pragma unroll
        for (int m = 1; m < 16; m <<= 1) ssum += __shfl_xor(ssum, m, 16);
        const float inv = 1.0f / ssum;
        for (int k = l16; k < LSx; k += 16) scs[h * 132 + k] *= inv;
      }
    }
    __syncthreads();

    if (tid < 48) {
      const int h = tid / 6;
      float a = 0.f;
      for (int k = 0; k < LSx; ++k) a += scs[h * 132 + k] * __half2float(vhs_h[k * 48 + tid]);
      osm[tid] = a;
    }
    __syncthreads();
    if (tid < 48) {
      float r = sbo[tid];
      for (int j = 0; j < 48; ++j) r += osm[j] * sWo[j * 48 + tid];
      sint[b * 48 + tid] = r;
    }
  } else {
    // =================== top-k + long MHA (K=48) =========================
    const int b = bid - BB;
    signed char* scS = (signed char*)pool;                  // 2048
    __half* vhs_h = (__half*)(pool + 2048);                 // 4608
    float* scs = (float*)(pool + 6656);                     // 8*52*4 = 1664
    float* Xitem = (float*)(pool + 8320);                   // 192
    float* qh = (float*)(pool + 8512);                      // 192
    float* osm = (float*)(pool + 8704);                     // 192
    int* selL = (int*)(pool + 8896);                        // 192
    int* hist = (int*)(pool + 9088);                        // 72
    int* wsum = (int*)(pool + 9160);                        // 8
    int* cnt_above = (int*)(pool + 9168);                   // 4
    unsigned char* validf = (unsigned char*)(pool + 9172);  // 48

    ((int4*)scS)[tid] = ((const int4*)(scoresG + (size_t)b * LLx))[tid];
    if (tid < 48) {
      const int seg = tid >> 4, e = tid & 15;
      const int id = (seg == 0) ? ig[b] : (seg == 1) ? ish[b] : ici[b];
      Xitem[tid] = emb[(size_t)id * 16 + e];
    }
    if (tid < 18) hist[tid] = 0;
    if (tid == 0) *cnt_above = 0;
    __syncthreads();

    #pragma unroll
    for (int j = 0; j < 16; ++j)
      atomicAdd(&hist[scS[tid * 16 + j] + 1], 1);
    if (tid < 48) {   // overlap: q projection
      float a = lbq[tid];
      for (int e = 0; e < 48; ++e) a += Xitem[e] * lWq[e * 48 + tid];
      qh[tid] = a;
    }
    __syncthreads();

    // threshold (identical on all threads)
    int above = 0, tval = -1, need = 0;
    for (int s = 16; s >= -1; --s) {
      const int c = hist[s + 1];
      if (above + c >= TOPKx) { tval = s; need = TOPKx - above; break; }
      above += c;
    }

    // tie ranking: 16 consecutive positions per thread + 128-thread scan
    int cnt = 0;
    #pragma unroll
    for (int j = 0; j < 16; ++j) cnt += (scS[tid * 16 + j] == tval) ? 1 : 0;
    int v = cnt;
    #pragma unroll
    for (int o = 1; o < 64; o <<= 1) {
      const int u = __shfl_up(v, o, 64);
      if (lane >= o) v += u;
    }
    if (lane == 63) wsum[wv] = v;
    __syncthreads();
    int rank = v - cnt + ((wv == 1) ? wsum[0] : 0);

    #pragma unroll
    for (int j = 0; j < 16; ++j) {
      const int l = tid * 16 + j;
      const int s = scS[l];
      if (s > tval) {
        const int slot = atomicAdd(cnt_above, 1);
        selL[slot] = l;
      } else if (s == tval) {
        if (rank < need) selL[above + rank] = l;
        ++rank;
      }
    }
    __syncthreads();

    int gid = 0, sid = 0, cid = 0;
    if (tid < TOPKx) {
      const int pos = selL[tid];
      gid = lg[(size_t)b * LLx + pos];
      sid = ls[(size_t)b * LLx + pos];
      cid = lcd[(size_t)b * LLx + pos];
      validf[tid] = (unsigned char)(gid != 0);   // long mask = gid != 0
    }
    const int nval = __syncthreads_count(tid < TOPKx && gid != 0);

    if (tid < TOPKx) {
      float kh[48], vh[48];
      #pragma unroll
      for (int j = 0; j < 48; ++j) { kh[j] = lbk[j]; vh[j] = lbv[j]; }
      const int ids3[3] = {gid, sid, cid};
      #pragma unroll
      for (int seg = 0; seg < 3; ++seg) {
        const float* row = emb + (size_t)ids3[seg] * 16;
        #pragma unroll
        for (int i4 = 0; i4 < 4; ++i4) {
          const float4 xv = ((const float4*)row)[i4];
          const float xs[4] = {xv.x, xv.y, xv.z, xv.w};
          #pragma unroll
          for (int c = 0; c < 4; ++c) {
            const float* wkr = lWk + (seg * 16 + i4 * 4 + c) * 48;
            const float* wvr = lWv + (seg * 16 + i4 * 4 + c) * 48;
            const float xe = xs[c];
            #pragma unroll
            for (int j = 0; j < 48; ++j) {
              kh[j] += xe * wkr[j];
              vh[j] += xe * wvr[j];
            }
          }
        }
      }
      #pragma unroll
      for (int h = 0; h < 8; ++h) {
        float s = 0.f;
        #pragma unroll
        for (int d = 0; d < 6; ++d) s += qh[h * 6 + d] * kh[h * 6 + d];
        scs[h * 52 + tid] = s * 0.40824829046386301637f;
      }
      #pragma unroll
      for (int j = 0; j < 48; ++j) vhs_h[tid * 48 + j] = __float2half(vh[j]);
    }
    __syncthreads();

    {  // softmax
      const int h = tid >> 4, l16 = tid & 15;
      float amax = -INFINITY;
      for (int k = l16; k < TOPKx; k += 16) if (validf[k]) amax = fmaxf(amax, scs[h * 52 + k]);
      #pragma unroll
      for (int m = 1; m < 16; m <<= 1) amax = fmaxf(amax, __shfl_xor(amax, m, 16));
      if (nval == 0) {
        for (int k = l16; k < TOPKx; k += 16) scs[h * 52 + k] = 1.0f / (float)TOPKx;
      } else {
        float ssum = 0.f;
        for (int k = l16; k < TOPKx; k += 16) {
          const float ev = validf[k] ? expf(scs[h * 52 + k] - amax) : 0.f;
          scs[h * 52 + k] = ev;
          ssum += ev;
        }
        #pragma unroll
        for (int m = 1; m < 16; m <<= 1) ssum += __shfl_xor(ssum, m, 16);
        const float inv = 1.0f / ssum;
        for (int k = l16; k < TOPKx; k += 16) scs[h * 52 + k] *= inv;
      }
    }
    __syncthreads();

    if (tid < 48) {
      const int h = tid / 6;
      float a = 0.f;
      for (int k = 0; k < TOPKx; ++k) a += scs[h * 52 + k] * __half2float(vhs_h[k * 48 + tid]);
      osm[tid] = a;
    }
    __syncthreads();
    if (tid < 48) {
      float r = lbo[tid];
      for (int j = 0; j < 48; ++j) r += osm[j] * lWo[j * 48 + tid];
      lint[b * 48 + tid] = r;
    }
  }
}

// ---------------------------------------------------------------------------
// Kernel 4: MLP head (one block per batch elem)
// ---------------------------------------------------------------------------
__device__ __forceinline__ float block_sum256(float v, float* red) {
  #pragma unroll
  for (int m = 32; m >= 1; m >>= 1) v += __shfl_xor(v, m, 64);
  const int lane = threadIdx.x & 63, wave = threadIdx.x >> 6;
  if (lane == 0) red[wave] = v;
  __syncthreads();
  const float t = red[0] + red[1] + red[2] + red[3];
  __syncthreads();
  return t;
}

__global__ __launch_bounds__(256) void k_mlp(
    const int* __restrict__ uid, const int* __restrict__ u1, const int* __restrict__ u2,
    const int* __restrict__ u3, const int* __restrict__ u4,
    const int* __restrict__ ig, const int* __restrict__ ish, const int* __restrict__ ici,
    const float* __restrict__ emb,
    const float* __restrict__ sint, const float* __restrict__ lint,
    const float* __restrict__ W1, const float* __restrict__ b1,
    const float* __restrict__ g1, const float* __restrict__ be1,
    const float* __restrict__ W2, const float* __restrict__ b2,
    const float* __restrict__ g2, const float* __restrict__ be2,
    const float* __restrict__ W3, const float* __restrict__ b3,
    float* __restrict__ out)
{
  __shared__ __align__(16) float x[224];
  __shared__ __align__(16) float h1[200];
  __shared__ float h2[80];
  __shared__ float red[4];
  const int b = blockIdx.x, tid = threadIdx.x;

  if (tid < 128) {
    const int e = tid & 15;
    int id;
    if (tid < 48) {
      const int seg = tid >> 4;
      id = (seg == 0) ? ig[b] : (seg == 1) ? ish[b] : ici[b];
    } else {
      const int f = (tid - 48) >> 4;
      id = (f == 0) ? uid[b] : (f == 1) ? u1[b] : (f == 2) ? u2[b] : (f == 3) ? u3[b] : u4[b];
    }
    x[tid] = emb[(size_t)id * 16 + e];
  } else if (tid < 176) {
    x[tid] = sint[b * 48 + (tid - 128)];
  } else if (tid < 224) {
    x[tid] = lint[b * 48 + (tid - 176)];
  }
  __syncthreads();

  float v = 0.f;
  if (tid < 200) {
    float a0 = b1[tid], a1 = 0.f, a2 = 0.f, a3 = 0.f;
    for (int i4 = 0; i4 < 56; ++i4) {
      const float4 xv = *(const float4*)(x + i4 * 4);
      const float* w = W1 + i4 * 4 * 200 + tid;
      a0 += xv.x * w[0];
      a1 += xv.y * w[200];
      a2 += xv.z * w[400];
      a3 += xv.w * w[600];
    }
    v = (a0 + a1) + (a2 + a3);
  }
  const float mean1 = block_sum256((tid < 200) ? v : 0.f, red) * (1.0f / 200.0f);
  const float dv = (tid < 200) ? (v - mean1) : 0.f;
  const float var1 = block_sum256(dv * dv, red) * (1.0f / 200.0f);
  if (tid < 200) {
    const float y = (v - mean1) * rsqrtf(var1 + 1e-3f) * g1[tid] + be1[tid];
    h1[tid] = fmaxf(y, 0.f);
  }
  __syncthreads();

  float v2 = 0.f;
  if (tid < 80) {
    float a0 = b2[tid], a1 = 0.f, a2 = 0.f, a3 = 0.f;
    for (int i4 = 0; i4 < 50; ++i4) {
      const float4 xv = *(const float4*)(h1 + i4 * 4);
      const float* w = W2 + i4 * 4 * 80 + tid;
      a0 += xv.x * w[0];
      a1 += xv.y * w[80];
      a2 += xv.z * w[160];
      a3 += xv.w * w[240];
    }
    v2 = (a0 + a1) + (a2 + a3);
  }
  const float mean2 = block_sum256((tid < 80) ? v2 : 0.f, red) * (1.0f / 80.0f);
  const float dv2 = (tid < 80) ? (v2 - mean2) : 0.f;
  const float var2 = block_sum256(dv2 * dv2, red) * (1.0f / 80.0f);
  if (tid < 80) {
    const float y = (v2 - mean2) * rsqrtf(var2 + 1e-3f) * g2[tid] + be2[tid];
    h2[tid] = fmaxf(y, 0.f);
  }
  __syncthreads();

  const float p = (tid < 80) ? h2[tid] * W3[tid] : 0.f;
  const float z = block_sum256(p, red);
  if (tid == 0) {
    out[b] = 1.0f / (1.0f + expf(-(z + b3[0])));
  }
}

// ---------------------------------------------------------------------------
extern "C" void kernel_launch(void* const* d_in, const int* in_sizes, int n_in,
                              void* d_out, int out_size, void* d_ws, size_t ws_size,
                              hipStream_t stream) {
  (void)in_sizes; (void)n_in; (void)out_size; (void)ws_size;
  const int* uid = (const int*)d_in[0];
  const int* u1  = (const int*)d_in[1];
  const int* u2  = (const int*)d_in[2];
  const int* u3  = (const int*)d_in[3];
  const int* u4  = (const int*)d_in[4];
  const int* ig  = (const int*)d_in[5];
  const int* ish = (const int*)d_in[6];
  const int* ici = (const int*)d_in[7];
  const int* sg  = (const int*)d_in[8];
  const int* ss  = (const int*)d_in[9];
  const int* scd = (const int*)d_in[10];
  const int* lg  = (const int*)d_in[11];
  const int* ls  = (const int*)d_in[12];
  const int* lcd = (const int*)d_in[13];
  const float* emb = (const float*)d_in[14];
  const float* Hm  = (const float*)d_in[15];
  const float* sWq = (const float*)d_in[16];
  const float* sbq = (const float*)d_in[17];
  const float* sWk = (const float*)d_in[18];
  const float* sbk = (const float*)d_in[19];
  const float* sWv = (const float*)d_in[20];
  const float* sbv = (const float*)d_in[21];
  const float* sWo = (const float*)d_in[22];
  const float* sbo = (const float*)d_in[23];
  const float* lWq = (const float*)d_in[24];
  const float* lbq = (const float*)d_in[25];
  const float* lWk = (const float*)d_in[26];
  const float* lbk = (const float*)d_in[27];
  const float* lWv = (const float*)d_in[28];
  const float* lbv = (const float*)d_in[29];
  const float* lWo = (const float*)d_in[30];
  const float* lbo = (const float*)d_in[31];
  const float* W1 = (const float*)d_in[32];
  const float* b1 = (const float*)d_in[33];
  const float* g1 = (const float*)d_in[34];
  const float* be1 = (const float*)d_in[35];
  const float* W2 = (const float*)d_in[36];
  const float* b2 = (const float*)d_in[37];
  const float* g2 = (const float*)d_in[38];
  const float* be2 = (const float*)d_in[39];
  const float* W3 = (const float*)d_in[40];
  const float* b3 = (const float*)d_in[41];
  float* out = (float*)d_out;

  float* sint = (float*)d_ws;                              //   196,608 B
  float* lint = sint + BB * 48;                            //   196,608 B
  int* icodesG = (int*)(lint + BB * 48);                   //    65,536 B
  signed char* scoresG = (signed char*)(icodesG + BB * 16);//  2,097,152 B
  __half* Ph = (__half*)(scoresG + (size_t)BB * LLx);      // 15,360,000 B  (~17.9 MB total)

  k_pre<<<dim3(629), dim3(256), 0, stream>>>(emb, Hm, ig, ish, ici, Ph, icodesG);
  k_codes<<<dim3(4 * BB), dim3(256), 0, stream>>>(lg, ls, lcd, icodesG, Ph, scoresG);
  k_att<<<dim3(2 * BB), dim3(128), 0, stream>>>(
      sg, ss, scd, lg, ls, lcd, ig, ish, ici, emb, scoresG,
      sWq, sbq, sWk, sbk, sWv, sbv, sWo, sbo,
      lWq, lbq, lWk, lbk, lWv, lbv, lWo, lbo,
      sint, lint);
  k_mlp<<<dim3(BB), dim3(256), 0, stream>>>(
      uid, u1, u2, u3, u4, ig, ish, ici, emb,
      sint, lint, W1, b1, g1, be1, W2, b2, g2, be2, W3, b3, out);
}